// Round 4
// baseline (396.433 us; speedup 1.0000x reference)
//
#include <hip/hip_runtime.h>
#include <hip/hip_bf16.h>

typedef __attribute__((ext_vector_type(8))) short short8;
typedef __attribute__((ext_vector_type(4))) float f32x4;
typedef unsigned short u16;

#define DIM     1024
#define NHEAD   16
#define HDIM    64
#define AS1 __attribute__((address_space(1)))
#define AS3 __attribute__((address_space(3)))

__device__ __forceinline__ u16 f2b(float f) {
  union { float f; unsigned u; } v; v.f = f;
  unsigned r = (v.u + 0x7FFFu + ((v.u >> 16) & 1u)) >> 16;
  return (u16)r;
}

// ---------------- convert x fp32 -> bf16 ------------------------------------
__global__ void cvt_x_kernel(const float* __restrict__ in, u16* __restrict__ out, int n8) {
  int i = blockIdx.x * 256 + threadIdx.x;
  if (i >= n8) return;
  const float4* p = (const float4*)in + (size_t)i * 2;
  float4 a = p[0], c = p[1];
  short8 o;
  o[0] = (short)f2b(a.x); o[1] = (short)f2b(a.y); o[2] = (short)f2b(a.z); o[3] = (short)f2b(a.w);
  o[4] = (short)f2b(c.x); o[5] = (short)f2b(c.y); o[6] = (short)f2b(c.z); o[7] = (short)f2b(c.w);
  *((short8*)out + i) = o;
}

// ------------- convert W (K,N) fp32 -> W^T (N,K) bf16, 3 matrices -----------
__global__ void cvt_wT_kernel(const float* __restrict__ Wq, const float* __restrict__ Wk,
                              const float* __restrict__ Wv, u16* __restrict__ wT) {
  int t = blockIdx.x * 256 + threadIdx.x;
  int mat = t >> 17;
  int rem = t & 131071;
  int kg  = rem >> 10;
  int n   = rem & 1023;
  const float* W = (mat == 0) ? Wq : (mat == 1) ? Wk : Wv;
  short8 v;
  #pragma unroll
  for (int i = 0; i < 8; ++i) v[i] = (short)f2b(W[(size_t)(kg * 8 + i) * DIM + n]);
  *(short8*)(wT + ((size_t)mat << 20) + (size_t)n * DIM + kg * 8) = v;
}

// ---------------- QKV GEMM: 256x256 tile, BK=64, deep 8-phase schedule ------
// 512 thr = 8 waves (2M x 4N), per-wave 128x64 out (acc[8][4] f32x4).
// LDS: 2 dbuf x { A[256][64] | B[256][64] } bf16 = 128 KiB; K-tile j -> dbuf[j&1].
// Stage chunks aligned to read-sets (reads stripe across wave rows):
//   A_e = rows {0-63,128-191}   read only phase 1 (LDA g0)
//   A_o = rows {64-127,192-255} read only phase 3 (LDA g1)
//   B_e = rows = [0,32) mod 64  read only phase 1 (b01)
//   B_o = rows = [32,64) mod 64 read only phase 2 (b23)
// Group j (4 phases): ph2 stages (j+2).A_e,(j+2).B_e; ph3 (j+2).B_o; ph4 (j+2).A_o
//   -> every piece is staged 7 phases before its guard.
// Guards (counted, never 0 until tail): end-ph1 vmcnt(10) forces (j).B_o... i.e.
//   end-ph1 of j: force (j).B_o? no: forces (j)'s successor needs -- see table:
//   end-ph1: vmcnt(10) forces (j+1... [derivation in session notes]:
//   end-ph1 of j forces (j).B_o-needed-next? Concretely: G1 forces the B_o of
//   this group's K-tile consumed at ph2; G2 forces A_o (ph3); G4 forces
//   (j+1).A_e,B_e (ph1 of next group). Steady-state counts: G1=10, G2=12, G4=12.
//   Tail (j=14): 10/8/4; (j=15): 2/0/0.
// Swizzle: 16B-slot XOR phys = logical ^ (row&7); staged via pre-swizzled
// global src + linear LDS dest (chunk bases are multiples of 8 so row&7 is
// lane-local and identical on write/read sides).
#define VMW_(n) asm volatile("s_waitcnt vmcnt(" #n ")" ::: "memory")
#define VMW(n) VMW_(n)

#define STAGE_P(isB, isOdd, ktile) do { \
  _Pragma("unroll") \
  for (int _j = 0; _j < 2; ++_j) { \
    int _b = _j * 8 + wid; \
    int _r0 = (isB) ? (((_b >> 2) << 6) + ((_b & 3) << 3) + ((isOdd) << 5)) \
                    : (((_b >> 3) << 7) + ((_b & 7) << 3) + ((isOdd) << 6)); \
    __builtin_amdgcn_global_load_lds( \
      (const AS1 void*)(((isB) ? srcB : srcA) + (size_t)_r0 * DIM + (ktile) * 64), \
      (AS3 void*)(lds + ((((ktile) & 1) << 15) + ((isB) << 14) + _r0 * 64)), \
      16, 0, 0); \
  } \
} while (0)

#define LDA(d, g) do { \
  _Pragma("unroll") \
  for (int _mi = 0; _mi < 4; ++_mi) { \
    int _r = abase + ((g) * 4 + _mi) * 1024 + ((d) << 15); \
    a[_mi * 2]     = *(const short8*)(lds + _r + sx0); \
    a[_mi * 2 + 1] = *(const short8*)(lds + _r + sx1); \
  } \
} while (0)

#define LDB(d, dst, nB) do { \
  _Pragma("unroll") \
  for (int _ni = 0; _ni < 2; ++_ni) { \
    int _r = bbase + ((nB) + _ni) * 1024 + ((d) << 15) + 16384; \
    dst[_ni * 2]     = *(const short8*)(lds + _r + sx0); \
    dst[_ni * 2 + 1] = *(const short8*)(lds + _r + sx1); \
  } \
} while (0)

#define MF(g, nB, bset) do { \
  _Pragma("unroll") \
  for (int _mi = 0; _mi < 4; ++_mi) \
    _Pragma("unroll") \
    for (int _ni = 0; _ni < 2; ++_ni) \
      _Pragma("unroll") \
      for (int _kk = 0; _kk < 2; ++_kk) \
        acc[(g) * 4 + _mi][(nB) + _ni] = __builtin_amdgcn_mfma_f32_16x16x32_bf16( \
            a[_mi * 2 + _kk], bset[_ni * 2 + _kk], acc[(g) * 4 + _mi][(nB) + _ni], 0, 0, 0); \
} while (0)

#define PH_MID() do { \
  __builtin_amdgcn_s_barrier(); \
  asm volatile("s_waitcnt lgkmcnt(0)" ::: "memory"); \
  __builtin_amdgcn_sched_barrier(0); \
  __builtin_amdgcn_s_setprio(1); \
} while (0)

// One K-tile (4 phases). d = dbuf, j2 = K-tile staged (j+2), DOST = stage?
#define GROUP(d, j2, DOST, G1n, G2n, G4n) do { \
  /* phase 1: reads A_e(g0) + B_e(b01) */ \
  LDA(d, 0); LDB(d, b01, 0); \
  asm volatile("s_waitcnt lgkmcnt(8)" ::: "memory"); \
  PH_MID(); MF(0, 0, b01); \
  __builtin_amdgcn_s_setprio(0); VMW(G1n); __builtin_amdgcn_s_barrier(); \
  /* phase 2: reads B_o(b23); stage (j+2).A_e, (j+2).B_e */ \
  LDB(d, b23, 2); \
  if (DOST) { STAGE_P(0, 0, j2); STAGE_P(1, 0, j2); } \
  PH_MID(); MF(0, 2, b23); \
  __builtin_amdgcn_s_setprio(0); VMW(G2n); __builtin_amdgcn_s_barrier(); \
  /* phase 3: reads A_o(g1); stage (j+2).B_o */ \
  LDA(d, 1); \
  if (DOST) STAGE_P(1, 1, j2); \
  PH_MID(); MF(1, 2, b23); \
  __builtin_amdgcn_s_setprio(0); __builtin_amdgcn_s_barrier(); \
  /* phase 4: all-reg; stage (j+2).A_o */ \
  if (DOST) STAGE_P(0, 1, j2); \
  PH_MID(); MF(1, 0, b01); \
  __builtin_amdgcn_s_setprio(0); VMW(G4n); __builtin_amdgcn_s_barrier(); \
} while (0)

__global__ __launch_bounds__(512, 2) void qkv_gemm_kernel(
    const u16* __restrict__ xb, const u16* __restrict__ wT,
    const float* __restrict__ bq, const float* __restrict__ bk, const float* __restrict__ bv,
    u16* __restrict__ qb, u16* __restrict__ kb, u16* __restrict__ vb)
{
  __shared__ u16 lds[65536];   // 128 KiB

  const int tid  = threadIdx.x;
  const int lane = tid & 63;
  const int wid  = tid >> 6;

  // XCD-chunked bijective swizzle: 1536 = 8 XCDs x 192
  const int orig = blockIdx.x;
  const int wg   = (orig & 7) * 192 + (orig >> 3);
  const int bm   = wg / 12;
  const int bn   = wg % 12;
  const int mat  = bn >> 2;
  const int col0 = (bn & 3) << 8;
  const int row0 = bm << 8;
  const u16* Wm = wT + ((size_t)mat << 20);
  const float* bias = (mat == 0) ? bq : (mat == 1) ? bk : bv;
  u16* outp = (mat == 0) ? qb : (mat == 1) ? kb : vb;

  const int wr = wid >> 2;             // 0..1
  const int wc = wid & 3;              // 0..3
  const int l15 = lane & 15, lhi = lane >> 4;

  // staging source (pre-swizzled so LDS dest stays linear)
  const int sr = lane >> 3;            // row within 8-row block
  const int sl = (lane & 7) ^ sr;      // logical 16B slot
  const u16* srcA = xb + (size_t)(row0 + sr) * DIM + sl * 8;
  const u16* srcB = Wm + (size_t)(col0 + sr) * DIM + sl * 8;

  // fragment phys-slot offsets (elems): phys = logical ^ (row&7)
  const int sx0 = (lhi ^ (l15 & 7)) << 3;
  const int sx1 = ((4 + lhi) ^ (l15 & 7)) << 3;
  const int abase = (wr * 128 + l15) * 64;
  const int bbase = (wc * 64 + l15) * 64;

  f32x4 acc[8][4] = {};
  short8 a[8], b01[4], b23[4];

  // prologue: K-tiles 0 and 1 fully staged; (0) forced, (1)'s 8 loads in flight
  STAGE_P(0, 0, 0); STAGE_P(1, 0, 0); STAGE_P(1, 1, 0); STAGE_P(0, 1, 0);
  STAGE_P(0, 0, 1); STAGE_P(1, 0, 1); STAGE_P(1, 1, 1); STAGE_P(0, 1, 1);
  VMW(8);
  __builtin_amdgcn_s_barrier();

  #pragma unroll 1
  for (int t = 0; t < 7; ++t) {
    GROUP(0, 2 * t + 2, 1, 10, 12, 12);
    GROUP(1, 2 * t + 3, 1, 10, 12, 12);
  }
  // tail: groups j=14, j=15 (no stages; guards drain precisely)
  GROUP(0, 16, 0, 10, 8, 4);
  GROUP(1, 17, 0, 2, 0, 0);

  // epilogue: bias + bf16 store. C/D: col = l15, row = lhi*4 + r
  #pragma unroll
  for (int ni = 0; ni < 4; ++ni) {
    int gcol = col0 + wc * 64 + ni * 16 + l15;
    float bb = bias[gcol];
    #pragma unroll
    for (int mi = 0; mi < 8; ++mi) {
      int grow = row0 + wr * 128 + mi * 16 + (lhi << 2);
      #pragma unroll
      for (int r = 0; r < 4; ++r)
        outp[(size_t)(grow + r) * DIM + gcol] = f2b(acc[mi][ni][r] + bb);
    }
  }
}

// ---------------- block-diagonal attention: one WG per (b, blk, h) -----------
__global__ __launch_bounds__(256) void blk_attn_kernel(
    const u16* __restrict__ qb, const u16* __restrict__ kb, const u16* __restrict__ vb,
    float* __restrict__ out)
{
  __shared__ u16 qs[64 * 72];
  __shared__ u16 ks[64 * 72];
  __shared__ u16 vts[64 * 72];
  __shared__ u16 ps[64 * 72];

  const int tid  = threadIdx.x;
  const int lane = tid & 63;
  const int wid  = tid >> 6;
  const int idx  = blockIdx.x;
  const int h    = idx & 15;
  const int blk  = (idx >> 4) & 127;
  const int b    = idx >> 11;
  const size_t s0 = (size_t)b * 8192 + (size_t)blk * 64;
  const int h0 = h * HDIM;

  {
    int i  = tid >> 2;
    int cg = (tid & 3) * 16;
    const u16* qg = qb + (s0 + i) * DIM + h0 + cg;
    *(short8*)(qs + i * 72 + cg)     = *(const short8*)qg;
    *(short8*)(qs + i * 72 + cg + 8) = *(const short8*)(qg + 8);
    const u16* kg = kb + (s0 + i) * DIM + h0 + cg;
    *(short8*)(ks + i * 72 + cg)     = *(const short8*)kg;
    *(short8*)(ks + i * 72 + cg + 8) = *(const short8*)(kg + 8);
    const u16* vg = vb + (s0 + i) * DIM + h0 + cg;
    short8 v0 = *(const short8*)vg;
    short8 v1 = *(const short8*)(vg + 8);
    #pragma unroll
    for (int e = 0; e < 8; ++e) {
      vts[(cg + e) * 72 + i]     = (u16)v0[e];
      vts[(cg + 8 + e) * 72 + i] = (u16)v1[e];
    }
  }
  __syncthreads();

  f32x4 S[4] = {};
  {
    short8 aq[2];
    #pragma unroll
    for (int kk = 0; kk < 2; ++kk)
      aq[kk] = *(const short8*)(qs + (wid * 16 + (lane & 15)) * 72 + kk * 32 + ((lane >> 4) << 3));
    #pragma unroll
    for (int jt = 0; jt < 4; ++jt)
      #pragma unroll
      for (int kk = 0; kk < 2; ++kk) {
        short8 bk_ = *(const short8*)(ks + (jt * 16 + (lane & 15)) * 72 + kk * 32 + ((lane >> 4) << 3));
        S[jt] = __builtin_amdgcn_mfma_f32_16x16x32_bf16(aq[kk], bk_, S[jt], 0, 0, 0);
      }
  }

  const float scale = 0.125f;
  float rinv[4];
  #pragma unroll
  for (int r = 0; r < 4; ++r) {
    float m = S[0][r] * scale;
    #pragma unroll
    for (int jt = 1; jt < 4; ++jt) m = fmaxf(m, S[jt][r] * scale);
    #pragma unroll
    for (int off = 1; off < 16; off <<= 1) m = fmaxf(m, __shfl_xor(m, off, 64));
    float s = 0.f;
    #pragma unroll
    for (int jt = 0; jt < 4; ++jt) {
      float e = __expf(S[jt][r] * scale - m);
      S[jt][r] = e;
      s += e;
    }
    #pragma unroll
    for (int off = 1; off < 16; off <<= 1) s += __shfl_xor(s, off, 64);
    rinv[r] = 1.0f / s;
  }

  #pragma unroll
  for (int jt = 0; jt < 4; ++jt)
    #pragma unroll
    for (int r = 0; r < 4; ++r)
      ps[(wid * 16 + ((lane >> 4) << 2) + r) * 72 + jt * 16 + (lane & 15)] = f2b(S[jt][r]);
  __syncthreads();

  f32x4 O[4] = {};
  {
    short8 pa[2];
    #pragma unroll
    for (int kk = 0; kk < 2; ++kk)
      pa[kk] = *(const short8*)(ps + (wid * 16 + (lane & 15)) * 72 + kk * 32 + ((lane >> 4) << 3));
    #pragma unroll
    for (int dt = 0; dt < 4; ++dt)
      #pragma unroll
      for (int kk = 0; kk < 2; ++kk) {
        short8 bv_ = *(const short8*)(vts + (dt * 16 + (lane & 15)) * 72 + kk * 32 + ((lane >> 4) << 3));
        O[dt] = __builtin_amdgcn_mfma_f32_16x16x32_bf16(pa[kk], bv_, O[dt], 0, 0, 0);
      }
  }

  #pragma unroll
  for (int dt = 0; dt < 4; ++dt)
    #pragma unroll
    for (int r = 0; r < 4; ++r)
      out[(s0 + wid * 16 + ((lane >> 4) << 2) + r) * DIM + h0 + dt * 16 + (lane & 15)] = O[dt][r] * rinv[r];
}

extern "C" void kernel_launch(void* const* d_in, const int* in_sizes, int n_in,
                              void* d_out, int out_size, void* d_ws, size_t ws_size,
                              hipStream_t stream) {
  const float* x  = (const float*)d_in[0];
  const float* Wq = (const float*)d_in[1];
  const float* bq = (const float*)d_in[2];
  const float* Wk = (const float*)d_in[3];
  const float* bk = (const float*)d_in[4];
  const float* Wv = (const float*)d_in[5];
  const float* bv = (const float*)d_in[6];
  float* out = (float*)d_out;

  char* ws = (char*)d_ws;
  u16* xb = (u16*)ws;                          // 67,108,864 B
  u16* wT = (u16*)(ws + 67108864);             // 6,291,456 B
  u16* qb = (u16*)(ws + 73400320);             // 67,108,864 B
  u16* kb = (u16*)(ws + 140509184);            // 67,108,864 B
  u16* vb = (u16*)(ws + 207618048);            // 67,108,864 B

  cvt_x_kernel<<<16384, 256, 0, stream>>>(x, xb, 4194304);
  cvt_wT_kernel<<<1536, 256, 0, stream>>>(Wq, Wk, Wv, wT);
  qkv_gemm_kernel<<<1536, 512, 0, stream>>>(xb, wT, bq, bk, bv, qb, kb, vb);
  blk_attn_kernel<<<8192, 256, 0, stream>>>(qb, kb, vb, out);
}